// Round 9
// baseline (44240.808 us; speedup 1.0000x reference)
//
#include <hip/hip_runtime.h>
#include <math.h>
#include <stdint.h>

#define T_STEPS 2048
#define XDIM 118
#define EMBD 128
#define HD 1536
#define NA 96
#define NB 128
#define NBLK (NA + NB + 1)

// dynamic LDS: B = 3072(xv) + 36864(wl2) + 48(g1) + 24(c1) words = 160032 B
#define SMEM_BYTES 160608

typedef uint32_t u32x4 __attribute__((ext_vector_type(4)));  // 4-VGPR tuple for asm "v"

struct Params {
  const float *x, *h0in, *c0in;
  const float *Wih0, *Whh0, *bih0, *bhh0;
  const float *Wih1, *Whh1, *bih1, *bhh1;
  const float *Whl, *bhl, *Wout, *bout;
  const float *Wfold;
  float *PRE, *Wc, *bc;
  uint4 *h0rec, *h1rec, *partrec, *yrec;   // tagged-record mailboxes
  float *out;
};

__device__ __forceinline__ float bf_lo(uint32_t u){ return __uint_as_float(u << 16); }
__device__ __forceinline__ float bf_hi(uint32_t u){ return __uint_as_float(u & 0xffff0000u); }
__device__ __forceinline__ uint32_t packbf(float a, float b){
  uint32_t ua = __float_as_uint(a), ub = __float_as_uint(b);
  ua = (ua + 0x7fffu + ((ua >> 16) & 1u)) >> 16;           // RNE bf16 (low half)
  ub = (ub + 0x7fffu + ((ub >> 16) & 1u)) & 0xffff0000u;   // RNE bf16 (high half)
  return (ua & 0xffffu) | ub;
}
__device__ __forceinline__ float sigm(float x){ return 1.f / (1.f + __expf(-x)); }

// Tagged 16B record: {data0, data1, tag, 0}. One dwordx4 = one coherence-point
// transaction -> tag/data can't tear. sc0 sc1 = bypass L1/L2 (per-XCD L2s are
// not coherent); loads/stores meet at the device coherence point.
__device__ __forceinline__ u32x4 poll_rec(const uint4* p, uint32_t tag){
  u32x4 r; uint32_t n = 0;
  while (1){
    asm volatile("global_load_dwordx4 %0, %1, off sc0 sc1\n\ts_waitcnt vmcnt(0)"
                 : "=v"(r) : "v"(p) : "memory");
    if (r[2] >= tag) break;
    __builtin_amdgcn_s_sleep(2);
    if (++n > 2000000u) break;               // hang guard (wrong-result, not deadlock)
  }
  return r;
}
// dual-record poll: issue both loads, single waitcnt, retry until both tags land
__device__ __forceinline__ void poll2(const uint4* p0, const uint4* p1, uint32_t tag,
                                      float* d0, float* d1){
  u32x4 a, b; uint32_t n = 0;
  while (1){
    asm volatile("global_load_dwordx4 %0, %2, off sc0 sc1\n\t"
                 "global_load_dwordx4 %1, %3, off sc0 sc1\n\t"
                 "s_waitcnt vmcnt(0)"
                 : "=v"(a), "=v"(b) : "v"(p0), "v"(p1) : "memory");
    if (a[2] >= tag && b[2] >= tag) break;
    __builtin_amdgcn_s_sleep(2);
    if (++n > 2000000u) break;
  }
  *d0 = __uint_as_float(a[0]);
  *d1 = __uint_as_float(b[0]);
}
__device__ __forceinline__ u32x4 rec_issue(const uint4* p){
  u32x4 r;
  asm volatile("global_load_dwordx4 %0, %1, off sc0 sc1" : "=v"(r) : "v"(p) : "memory");
  return r;
}
__device__ __forceinline__ void st_rec(uint4* p, float a, float b, uint32_t tag){
  u32x4 v; v[0] = __float_as_uint(a); v[1] = __float_as_uint(b); v[2] = tag; v[3] = 0u;
  asm volatile("global_store_dwordx4 %0, %1, off sc0 sc1" :: "v"(p), "v"(v) : "memory");
}

// ---------------- group A: LSTM layer 0 + y-fold (96 blocks, 16 outputs each) ----------------
// wave w owns all 4 gates of output O=bid*16+w. xv is DOUBLE-BUFFERED ->
// only ONE barrier per step (post-staging); each wave's lane0 publishes its
// 1-float h0 record immediately after the gate math (in-band tag, no drain).
__device__ __forceinline__ float asrc(const Params& P, int r, int k){
  if (k < HD) return P.Whh0[(size_t)r * HD + k];
  return P.Wih0[(size_t)r * (XDIM + EMBD) + XDIM + (k - HD)];
}
__device__ void run_A(const Params& P, int bid, uint32_t* smem){
  const int tid = threadIdx.x;
  const int w = tid >> 6, l = tid & 63;
  const int O = bid * 16 + w;
  // LDS: xv[2][1536] words 0..3071; wl2 words 3072..19455
  uint2* wl2 = (uint2*)(smem + 3072);
  uint32_t wr[4][8];
  uint32_t wry[4];
#pragma unroll
  for (int g = 0; g < 4; ++g){
    int r = g * HD + O;
#pragma unroll
    for (int p = 0; p < 8; ++p)
      wr[g][p] = packbf(asrc(P, r, 128 * p + 2 * l), asrc(P, r, 128 * p + 2 * l + 1));
#pragma unroll
    for (int q = 0; q < 2; ++q){
      uint2 u;
      u.x = packbf(asrc(P, r, 128 * (8 + 2 * q) + 2 * l), asrc(P, r, 128 * (8 + 2 * q) + 2 * l + 1));
      u.y = packbf(asrc(P, r, 128 * (9 + 2 * q) + 2 * l), asrc(P, r, 128 * (9 + 2 * q) + 2 * l + 1));
      wl2[(q * 4 + g) * 1024 + tid] = u;
    }
    wry[g] = packbf(P.Wfold[(size_t)r * 128 + 2 * l], P.Wfold[(size_t)r * 128 + 2 * l + 1]);
  }
  float cst = P.c0in[O];
  __syncthreads();
  for (int t = 0; t < T_STEPS; ++t){
    const float* pre = P.PRE + (size_t)t * 6144;     // plain loads (read-only, cached)
    float q0 = pre[O], q1 = pre[HD + O], q2 = pre[2 * HD + O], q3 = pre[3 * HD + O];
    float* xv = (float*)smem + (t & 1) * 1536;       // parity buffer for this step
    // stage h0(t-1): 1536 one-float records, 2 per thread, fused detect+fetch
    if (tid < 768){
      const uint4* p = P.h0rec + ((t & 1) ^ 1) * 1536 + 2 * tid;
      poll2(p, p + 1, (uint32_t)t, &xv[2 * tid], &xv[2 * tid + 1]);
    }
    __syncthreads();                         // the ONLY barrier: xv staged
    float a0 = 0.f, a1 = 0.f, a2 = 0.f, a3 = 0.f;
#pragma unroll
    for (int p = 0; p < 8; ++p){
      float2 x2 = *(const float2*)&xv[128 * p + 2 * l];
      uint32_t u0 = wr[0][p], u1 = wr[1][p], u2 = wr[2][p], u3 = wr[3][p];
      a0 += bf_lo(u0) * x2.x + bf_hi(u0) * x2.y;
      a1 += bf_lo(u1) * x2.x + bf_hi(u1) * x2.y;
      a2 += bf_lo(u2) * x2.x + bf_hi(u2) * x2.y;
      a3 += bf_lo(u3) * x2.x + bf_hi(u3) * x2.y;
    }
#pragma unroll
    for (int q = 0; q < 2; ++q){
      float2 xa = *(const float2*)&xv[128 * (8 + 2 * q) + 2 * l];
      float2 xb = *(const float2*)&xv[128 * (9 + 2 * q) + 2 * l];
      uint2 u0 = wl2[(q * 4 + 0) * 1024 + tid];
      uint2 u1 = wl2[(q * 4 + 1) * 1024 + tid];
      uint2 u2 = wl2[(q * 4 + 2) * 1024 + tid];
      uint2 u3 = wl2[(q * 4 + 3) * 1024 + tid];
      a0 += bf_lo(u0.x) * xa.x + bf_hi(u0.x) * xa.y + bf_lo(u0.y) * xb.x + bf_hi(u0.y) * xb.y;
      a1 += bf_lo(u1.x) * xa.x + bf_hi(u1.x) * xa.y + bf_lo(u1.y) * xb.x + bf_hi(u1.y) * xb.y;
      a2 += bf_lo(u2.x) * xa.x + bf_hi(u2.x) * xa.y + bf_lo(u2.y) * xb.x + bf_hi(u2.y) * xb.y;
      a3 += bf_lo(u3.x) * xa.x + bf_hi(u3.x) * xa.y + bf_lo(u3.y) * xb.x + bf_hi(u3.y) * xb.y;
    }
    if (t > 0){                              // y(t-1): per-lane fused tagged poll
      u32x4 r = poll_rec(P.yrec + ((t & 1) ^ 1) * 64 + l, (uint32_t)t);
      float y0 = __uint_as_float(r[0]), y1 = __uint_as_float(r[1]);
      a0 += bf_lo(wry[0]) * y0 + bf_hi(wry[0]) * y1;
      a1 += bf_lo(wry[1]) * y0 + bf_hi(wry[1]) * y1;
      a2 += bf_lo(wry[2]) * y0 + bf_hi(wry[2]) * y1;
      a3 += bf_lo(wry[3]) * y0 + bf_hi(wry[3]) * y1;
    }
#pragma unroll
    for (int m = 1; m < 64; m <<= 1){
      a0 += __shfl_xor(a0, m, 64);
      a1 += __shfl_xor(a1, m, 64);
      a2 += __shfl_xor(a2, m, 64);
      a3 += __shfl_xor(a3, m, 64);
    }
    float gi = sigm(a0 + q0);
    float gf = sigm(a1 + q1);
    float gg = tanhf(a2 + q2);
    float go = sigm(a3 + q3);
    cst = gf * cst + gi * gg;
    float hn = go * tanhf(cst);
    // publish immediately per-wave: 1-float record, in-band tag, no barrier
    if (l == 0) st_rec(P.h0rec + (t & 1) * 1536 + O, hn, 0.f, (uint32_t)(t + 1));
    // xv(t+1) overwrite safety: staging at t+1 writes the OTHER parity buffer;
    // same-parity reuse (t+2) is ordered behind barrier1(t+1) transitively.
  }
}

// ---------------- group B: LSTM layer 1 + logit partials (128 blocks, 12 outputs) ----------------
// barriers 1-3 as round 6; barrier 4 REMOVED: partrec pairs assembled in-register
// (shfl_xor 4) and published straight from the gate phase; h1 published directly
// by tid 0..3 as 1-float records. All records carry in-band tags (no drains).
__device__ __forceinline__ float bsrc(const Params& P, int r, int k){
  if (k < HD) return P.Wih1[(size_t)r * HD + k];
  return P.Whh1[(size_t)r * HD + (k - HD)];
}
__device__ void run_B(const Params& P, int bidb, uint32_t* smem){
  const int tid = threadIdx.x;
  const int w = tid >> 6, l = tid & 63;
  const int base = bidb * 12;
  float* xv = (float*)smem;                  // 3072 floats (h0: 0..1535, h1: 1536..3071)
  uint2* wl2 = (uint2*)(smem + 3072);        // words 3072..39935 (147456 B)
  float* g1 = (float*)(smem + 39936);        // 48
  float* c1 = (float*)(smem + 39984);        // 2*12 double-buffered
  uint32_t wr[3][12];
  float bias[3];
#pragma unroll
  for (int jj = 0; jj < 3; ++jj){
    int idx = 3 * w + jj;
    int g = idx / 12, o = idx % 12;
    int r = g * HD + base + o;
    bias[jj] = P.bih1[r] + P.bhh1[r];
#pragma unroll
    for (int p = 0; p < 12; ++p)
      wr[jj][p] = packbf(bsrc(P, r, 128 * p + 2 * l), bsrc(P, r, 128 * p + 2 * l + 1));
#pragma unroll
    for (int q = 0; q < 6; ++q){
      uint2 u;
      u.x = packbf(bsrc(P, r, 128 * (12 + 2 * q) + 2 * l), bsrc(P, r, 128 * (12 + 2 * q) + 2 * l + 1));
      u.y = packbf(bsrc(P, r, 128 * (13 + 2 * q) + 2 * l), bsrc(P, r, 128 * (13 + 2 * q) + 2 * l + 1));
      wl2[(q * 3 + jj) * 1024 + tid] = u;
    }
  }
  const int jrow = tid >> 2, cpart = tid & 3;
  float wc0 = 0.f, wc1 = 0.f, wc2 = 0.f;
  if (tid < 512){
    const float* wcp = P.Wc + (size_t)jrow * HD + base + cpart * 3;
    wc0 = wcp[0]; wc1 = wcp[1]; wc2 = wcp[2];
  }
  if (tid < 12) c1[12 + tid] = P.c0in[HD + base + tid];   // t=0 reads buffer 1
  __syncthreads();
  for (int t = 0; t < T_STEPS; ++t){
    // stage h1(t-1): 1536 one-float records, tag >= t
    if (tid < 768){
      const uint4* p = P.h1rec + ((t & 1) ^ 1) * 1536 + 2 * tid;
      poll2(p, p + 1, (uint32_t)t, &xv[1536 + 2 * tid], &xv[1537 + 2 * tid]);
    }
    __syncthreads();                         // barrier 1
    float a0 = 0.f, a1 = 0.f, a2 = 0.f;
#pragma unroll
    for (int q = 0; q < 6; ++q){             // h1 side (LDS weights) — overlapped phase
      float2 xa = *(const float2*)&xv[128 * (12 + 2 * q) + 2 * l];
      float2 xb = *(const float2*)&xv[128 * (13 + 2 * q) + 2 * l];
      uint2 u0 = wl2[(q * 3 + 0) * 1024 + tid];
      uint2 u1 = wl2[(q * 3 + 1) * 1024 + tid];
      uint2 u2 = wl2[(q * 3 + 2) * 1024 + tid];
      a0 += bf_lo(u0.x) * xa.x + bf_hi(u0.x) * xa.y + bf_lo(u0.y) * xb.x + bf_hi(u0.y) * xb.y;
      a1 += bf_lo(u1.x) * xa.x + bf_hi(u1.x) * xa.y + bf_lo(u1.y) * xb.x + bf_hi(u1.y) * xb.y;
      a2 += bf_lo(u2.x) * xa.x + bf_hi(u2.x) * xa.y + bf_lo(u2.y) * xb.x + bf_hi(u2.y) * xb.y;
    }
    // stage h0(t): tag >= t+1 (the A->B hop; detect+fetch fused)
    if (tid < 768){
      const uint4* p = P.h0rec + (t & 1) * 1536 + 2 * tid;
      poll2(p, p + 1, (uint32_t)(t + 1), &xv[2 * tid], &xv[2 * tid + 1]);
    }
    __syncthreads();                         // barrier 2
#pragma unroll
    for (int p = 0; p < 12; ++p){            // h0 side (reg weights) — serial phase
      float2 x2 = *(const float2*)&xv[128 * p + 2 * l];
      uint32_t u0 = wr[0][p], u1 = wr[1][p], u2 = wr[2][p];
      a0 += bf_lo(u0) * x2.x + bf_hi(u0) * x2.y;
      a1 += bf_lo(u1) * x2.x + bf_hi(u1) * x2.y;
      a2 += bf_lo(u2) * x2.x + bf_hi(u2) * x2.y;
    }
#pragma unroll
    for (int m = 1; m < 64; m <<= 1){
      a0 += __shfl_xor(a0, m, 64);
      a1 += __shfl_xor(a1, m, 64);
      a2 += __shfl_xor(a2, m, 64);
    }
    if (l == 0){
      g1[3 * w + 0] = a0 + bias[0];
      g1[3 * w + 1] = a1 + bias[1];
      g1[3 * w + 2] = a2 + bias[2];
    }
    __syncthreads();                         // barrier 3
    const int par = ((t & 1) ^ 1) * 12, cur = (t & 1) * 12;
    uint32_t tg = (uint32_t)(t + 1);
    if (tid < 512){                          // fused gate + publish phase (no barrier 4)
      float h[3], cc[3];
#pragma unroll
      for (int ii = 0; ii < 3; ++ii){
        int o = cpart * 3 + ii;
        float gi = sigm(g1[o]);
        float gf = sigm(g1[12 + o]);
        float gg = tanhf(g1[24 + o]);
        float go = sigm(g1[36 + o]);
        float c = gf * c1[par + o] + gi * gg;
        cc[ii] = c;
        h[ii] = go * tanhf(c);
      }
      float pp = wc0 * h[0] + wc1 * h[1] + wc2 * h[2];
      pp += __shfl_xor(pp, 1, 64);
      pp += __shfl_xor(pp, 2, 64);           // all 4 cpart lanes now hold pp(jrow)
      float pp2 = __shfl_xor(pp, 4, 64);     // pair with jrow^1 (same wave)
      if ((tid & 7) == 0)                    // thread 8r: publish logits {2r, 2r+1}
        st_rec(P.partrec + (size_t)(t & 1) * 8192 + bidb * 64 + (tid >> 3), pp, pp2, tg);
      if (jrow == 0){                        // tid 0..3: c-state + direct h1 publish
#pragma unroll
        for (int ii = 0; ii < 3; ++ii){
          int o = cpart * 3 + ii;
          c1[cur + o] = cc[ii];
          st_rec(P.h1rec + (t & 1) * 1536 + base + o, h[ii], 0.f, tg);
        }
      }
    }
    // overwrite safety (no barrier 4): all next-step writers (xv, g1, c1) are
    // ordered behind barriers 1-3 of step t+1, which every wave reaches only
    // after completing its step-t reads. Publishes carry in-band tags.
  }
}

// ---------------- group C: logit reduce + softmax + y + out (1 block, 1 barrier/step) ----------------
__device__ void run_C(const Params& P, uint32_t* smem){
  const int tid = threadIdx.x;
  float* partred = (float*)smem;             // 2048
  float* bcs = (float*)(smem + 2048);        // 128
  const int w = tid >> 6, l = tid & 63;
  const int g8 = tid >> 6, j2 = tid & 63;    // 16 groups x 64
  if (tid < 128) bcs[tid] = P.bc[tid];
  __syncthreads();
  for (int t = 0; t < T_STEPS; ++t){
    const uint4* base = P.partrec + (size_t)(t & 1) * 8192;
    uint32_t tg = (uint32_t)(t + 1);
    u32x4 rec[8];
    uint32_t done = 0, n = 0;
    while (done != 0xFFu){                   // parallel poll: issue all stale, wait once
#pragma unroll
      for (int k = 0; k < 8; ++k)
        if (!(done & (1u << k))) rec[k] = rec_issue(base + (size_t)(8 * g8 + k) * 64 + j2);
      asm volatile("s_waitcnt vmcnt(0)" ::: "memory");
      __builtin_amdgcn_sched_barrier(0);     // pin the tag checks after the waitcnt
#pragma unroll
      for (int k = 0; k < 8; ++k)
        if (rec[k][2] >= tg) done |= (1u << k);
      if (done != 0xFFu){
        __builtin_amdgcn_s_sleep(2);
        if (++n > 2000000u) break;           // hang guard
      }
    }
    float s0 = 0.f, s1 = 0.f;
#pragma unroll
    for (int k = 0; k < 8; ++k){
      s0 += __uint_as_float(rec[k][0]);
      s1 += __uint_as_float(rec[k][1]);
    }
    partred[g8 * 128 + 2 * j2] = s0;
    partred[g8 * 128 + 2 * j2 + 1] = s1;
    __syncthreads();                         // the only barrier
    if (w == 0){                             // wave0 finishes the step alone
      float lt0 = bcs[2 * l], lt1 = bcs[2 * l + 1];
#pragma unroll
      for (int g = 0; g < 16; ++g){
        lt0 += partred[g * 128 + 2 * l];
        lt1 += partred[g * 128 + 2 * l + 1];
      }
      float m = fmaxf(lt0, lt1);
#pragma unroll
      for (int k = 1; k < 64; k <<= 1) m = fmaxf(m, __shfl_xor(m, k, 64));
      float e0 = __expf(lt0 - m), e1 = __expf(lt1 - m);
      float sd = e0 + e1;
#pragma unroll
      for (int k = 1; k < 64; k <<= 1) sd += __shfl_xor(sd, k, 64);
      float inv = 1.f / sd;
      float y0 = e0 * inv, y1 = e1 * inv;
      P.out[(size_t)t * 128 + 2 * l] = y0;   // host-only consumer: plain stores
      P.out[(size_t)t * 128 + 2 * l + 1] = y1;
      st_rec(P.yrec + (t & 1) * 64 + l, y0, y1, tg);
    }
    // next-step partred overwrite is gated transitively: tag t+2 requires B(t+1)
    // which requires A(t+1)'s y-poll of y(t), published after wave0's reads above.
  }
}

__global__ __launch_bounds__(1024) void k_lstm(Params P){
  extern __shared__ __align__(16) uint32_t smem[];
  int bid = blockIdx.x;
  if (bid < NA) run_A(P, bid, smem);
  else if (bid < NA + NB) run_B(P, bid - NA, smem);
  else run_C(P, smem);
}

// ---------------- pre-kernels ----------------
__global__ void k_init(const float* h0in, uint4* h0rec, uint4* h1rec,
                       uint4* partrec, uint4* yrec){
  int tid = threadIdx.x;
  for (int i = tid; i < 1536; i += 256){
    uint4 r0; r0.x = __float_as_uint(h0in[i]); r0.y = 0u; r0.z = 0u; r0.w = 0u;
    h0rec[i] = r0; h0rec[1536 + i] = r0;
    uint4 r1; r1.x = __float_as_uint(h0in[HD + i]); r1.y = 0u; r1.z = 0u; r1.w = 0u;
    h1rec[i] = r1; h1rec[1536 + i] = r1;
  }
  uint4 z; z.x = 0u; z.y = 0u; z.z = 0u; z.w = 0u;
  for (int i = tid; i < 16384; i += 256) partrec[i] = z;
  for (int i = tid; i < 128; i += 256) yrec[i] = z;
}

// Wfold[r][j] = sum_e Wih0[r][118+e] * Wmap[e][j]; bfold[r] = sum_e Wih0[r][118+e]*bmap[e]
__global__ void k_fold(const float* Wih0, const float* Wmap, const float* bmap,
                       float* Wfold, float* bfold){
  __shared__ float we[64 * 128];
  int b = blockIdx.x, tid = threadIdx.x;
  int r0 = b * 64;
  for (int i = tid; i < 64 * 128; i += 256){
    int rr = i >> 7, e = i & 127;
    we[i] = Wih0[(size_t)(r0 + rr) * (XDIM + EMBD) + XDIM + e];
  }
  __syncthreads();
  int j = tid & 127, half = tid >> 7;
  float acc[32];
#pragma unroll
  for (int rr = 0; rr < 32; ++rr) acc[rr] = 0.f;
  for (int e = 0; e < 128; ++e){
    float wv = Wmap[(size_t)e * 128 + j];
#pragma unroll
    for (int rr = 0; rr < 32; ++rr) acc[rr] += we[(half * 32 + rr) * 128 + e] * wv;
  }
  for (int rr = 0; rr < 32; ++rr)
    Wfold[(size_t)(r0 + half * 32 + rr) * 128 + j] = acc[rr];
  if (tid < 64){
    float a = 0.f;
    for (int e = 0; e < 128; ++e) a += we[tid * 128 + e] * bmap[e];
    bfold[r0 + tid] = a;
  }
}

// PRE[t][r] = b_ih0[r]+b_hh0[r] + (t>0 ? bfold[r] : 0) + sum_{k<118} W_ih0[r][k]*x[t][k]
__global__ void k_pre(const float* x, const float* Wih0, const float* bih0, const float* bhh0,
                      const float* bfold, float* PRE){
  int tb = blockIdx.x >> 2;
  int rc = blockIdx.x & 3;
  int tid = threadIdx.x;
  __shared__ float xl[32 * XDIM];
  for (int i = tid; i < 32 * XDIM; i += 256){
    int tt = i / XDIM, k = i % XDIM;
    xl[i] = x[(size_t)(tb * 32 + tt) * XDIM + k];
  }
  __syncthreads();
  for (int rr = 0; rr < 6; ++rr){
    int r = rc * HD + rr * 256 + tid;
    float acc[32];
#pragma unroll
    for (int t = 0; t < 32; ++t) acc[t] = 0.f;
    const float* wrow = Wih0 + (size_t)r * (XDIM + EMBD);
    for (int k = 0; k < XDIM; ++k){
      float wv = wrow[k];
#pragma unroll
      for (int t = 0; t < 32; ++t) acc[t] += wv * xl[t * XDIM + k];
    }
    float bb = bih0[r] + bhh0[r];
    float bf = bfold[r];
    for (int t = 0; t < 32; ++t)
      PRE[(size_t)(tb * 32 + t) * 6144 + r] = acc[t] + bb + ((tb * 32 + t) > 0 ? bf : 0.f);
  }
}

// Wc = W_out @ W_hl (128x1536, K=1024); bc = W_out @ b_hl + b_out
__global__ void k_wc(const float* Whl, const float* Wout, const float* bhl, const float* bout,
                     float* Wc, float* bc){
  if (blockIdx.x == 96){
    int j = threadIdx.x;
    if (j < 128){
      float a = 0.f;
      for (int m = 0; m < 1024; ++m) a += Wout[(size_t)j * 1024 + m] * bhl[m];
      bc[j] = a + bout[j];
    }
    return;
  }
  int kt = blockIdx.x % 6, jt = blockIdx.x / 6;
  __shared__ float wo[8 * 1024];
  int tid = threadIdx.x;
  for (int i = tid; i < 8 * 1024; i += 256) wo[i] = Wout[(size_t)(jt * 8) * 1024 + i];
  __syncthreads();
  int k = kt * 256 + tid;
  float acc[8];
#pragma unroll
  for (int jj = 0; jj < 8; ++jj) acc[jj] = 0.f;
  for (int m = 0; m < 1024; ++m){
    float wl = Whl[(size_t)m * HD + k];
#pragma unroll
    for (int jj = 0; jj < 8; ++jj) acc[jj] += wo[jj * 1024 + m] * wl;
  }
#pragma unroll
  for (int jj = 0; jj < 8; ++jj) Wc[(size_t)(jt * 8 + jj) * HD + k] = acc[jj];
}

__global__ void k_sentinel(float* out){ out[0] = 1.0e6f; }

extern "C" void kernel_launch(void* const* d_in, const int* in_sizes, int n_in,
                              void* d_out, int out_size, void* d_ws, size_t ws_size,
                              hipStream_t stream){
  (void)in_sizes; (void)n_in; (void)out_size;
  const float* x    = (const float*)d_in[0];
  const float* h0in = (const float*)d_in[1];
  const float* c0in = (const float*)d_in[2];
  const float* Wih0 = (const float*)d_in[3];
  const float* Whh0 = (const float*)d_in[4];
  const float* bih0 = (const float*)d_in[5];
  const float* bhh0 = (const float*)d_in[6];
  const float* Wih1 = (const float*)d_in[7];
  const float* Whh1 = (const float*)d_in[8];
  const float* bih1 = (const float*)d_in[9];
  const float* bhh1 = (const float*)d_in[10];
  const float* Whl  = (const float*)d_in[11];
  const float* bhl  = (const float*)d_in[12];
  const float* Wout = (const float*)d_in[13];
  const float* bout = (const float*)d_in[14];
  const float* Wmap = (const float*)d_in[15];
  const float* bmap = (const float*)d_in[16];
  float* out = (float*)d_out;
  float* ws = (float*)d_ws;

  size_t off = 0;
  float* PRE    = ws + off; off += (size_t)T_STEPS * 6144;
  float* Wc     = ws + off; off += 128 * HD;
  float* bc     = ws + off; off += 128;
  float* Wfold  = ws + off; off += (size_t)6144 * 128;
  float* bfold  = ws + off; off += 6144;
  off = (off + 3) & ~(size_t)3;              // 16B alignment for records
  uint4* h0rec   = (uint4*)(ws + off); off += 2 * 1536 * 4;
  uint4* h1rec   = (uint4*)(ws + off); off += 2 * 1536 * 4;
  uint4* partrec = (uint4*)(ws + off); off += 2 * 8192 * 4;
  uint4* yrec    = (uint4*)(ws + off); off += 2 * 64 * 4;

  if (ws_size < off * sizeof(float) + 1024){
    hipLaunchKernelGGL(k_sentinel, dim3(1), dim3(1), 0, stream, out);
    return;
  }

  // opt-in to >64KB dynamic LDS (160 KiB/CU on gfx950); unconditional, idempotent
  (void)hipFuncSetAttribute(reinterpret_cast<const void*>(k_lstm),
                            hipFuncAttributeMaxDynamicSharedMemorySize, SMEM_BYTES);

  hipLaunchKernelGGL(k_init, dim3(1), dim3(256), 0, stream, h0in, h0rec, h1rec, partrec, yrec);
  hipLaunchKernelGGL(k_fold, dim3(96), dim3(256), 0, stream, Wih0, Wmap, bmap, Wfold, bfold);
  hipLaunchKernelGGL(k_pre, dim3(256), dim3(256), 0, stream, x, Wih0, bih0, bhh0, bfold, PRE);
  hipLaunchKernelGGL(k_wc, dim3(97), dim3(256), 0, stream, Whl, Wout, bhl, bout, Wc, bc);

  Params P;
  P.x = x; P.h0in = h0in; P.c0in = c0in;
  P.Wih0 = Wih0; P.Whh0 = Whh0; P.bih0 = bih0; P.bhh0 = bhh0;
  P.Wih1 = Wih1; P.Whh1 = Whh1; P.bih1 = bih1; P.bhh1 = bhh1;
  P.Whl = Whl; P.bhl = bhl; P.Wout = Wout; P.bout = bout;
  P.Wfold = Wfold;
  P.PRE = PRE; P.Wc = Wc; P.bc = bc;
  P.h0rec = h0rec; P.h1rec = h1rec; P.partrec = partrec; P.yrec = yrec;
  P.out = out;

  hipLaunchKernelGGL(k_lstm, dim3(NBLK), dim3(1024), SMEM_BYTES, stream, P);
}

// Round 10
// 26790.009 us; speedup vs baseline: 1.6514x; 1.6514x over previous
//
#include <hip/hip_runtime.h>
#include <math.h>
#include <stdint.h>

#define T_STEPS 2048
#define XDIM 118
#define EMBD 128
#define HD 1536
#define NA 96
#define NB 128
#define NBLK (NA + NB + 1)

// dynamic LDS: B needs 3072(xv) + 36864(wl2) + 48(g1) + 24(c1) words
#define SMEM_BYTES 160608

typedef uint32_t u32x4 __attribute__((ext_vector_type(4)));  // 4-VGPR tuple for asm "v"

struct Params {
  const float *x, *h0in, *c0in;
  const float *Wih0, *Whh0, *bih0, *bhh0;
  const float *Wih1, *Whh1, *bih1, *bhh1;
  const float *Whl, *bhl, *Wout, *bout;
  const float *Wfold;
  float *PRE, *Wc, *bc;
  uint4 *h0rec, *h1rec, *partrec, *yrec;   // tagged-record mailboxes
  float *out;
};

__device__ __forceinline__ float bf_lo(uint32_t u){ return __uint_as_float(u << 16); }
__device__ __forceinline__ float bf_hi(uint32_t u){ return __uint_as_float(u & 0xffff0000u); }
__device__ __forceinline__ uint32_t packbf(float a, float b){
  uint32_t ua = __float_as_uint(a), ub = __float_as_uint(b);
  ua = (ua + 0x7fffu + ((ua >> 16) & 1u)) >> 16;           // RNE bf16 (low half)
  ub = (ub + 0x7fffu + ((ub >> 16) & 1u)) & 0xffff0000u;   // RNE bf16 (high half)
  return (ua & 0xffffu) | ub;
}
__device__ __forceinline__ float sigm(float x){ return 1.f / (1.f + __expf(-x)); }

// Tagged 16B record: {data0, data1, tag, 0}. One dwordx4 = one coherence-point
// transaction -> tag/data can't tear. sc0 sc1 = bypass L1/L2 (per-XCD L2s are
// not coherent); loads/stores meet at the device coherence point.
__device__ __forceinline__ u32x4 poll_rec(const uint4* p, uint32_t tag){
  u32x4 r; uint32_t n = 0;
  while (1){
    asm volatile("global_load_dwordx4 %0, %1, off sc0 sc1\n\ts_waitcnt vmcnt(0)"
                 : "=v"(r) : "v"(p) : "memory");
    if (r[2] >= tag) break;
    __builtin_amdgcn_s_sleep(2);
    if (++n > 2000000u) break;               // hang guard (wrong-result, not deadlock)
  }
  return r;
}
__device__ __forceinline__ u32x4 rec_issue(const uint4* p){
  u32x4 r;
  asm volatile("global_load_dwordx4 %0, %1, off sc0 sc1" : "=v"(r) : "v"(p) : "memory");
  return r;
}
__device__ __forceinline__ void st_rec(uint4* p, float a, float b, uint32_t tag){
  u32x4 v; v[0] = __float_as_uint(a); v[1] = __float_as_uint(b); v[2] = tag; v[3] = 0u;
  asm volatile("global_store_dwordx4 %0, %1, off sc0 sc1" :: "v"(p), "v"(v) : "memory");
}

// ---------------- group A: LSTM layer 0 + y-fold (96 blocks, 16 outputs each) ----------------
// wave w owns all 4 gates of output O=bid*16+w. K slots of 128: p=0..7 h0 (reg
// weights), p=8..11 h0 (LDS weights), final slot = y(t-1) via folded Wfold.
// Staging h0(t-1): threads 0..767 poll h0rec tags (detect+fetch fused).
// y(t-1): each lane polls its own yrec record. Publish: 8 tagged records.
__device__ __forceinline__ float asrc(const Params& P, int r, int k){
  if (k < HD) return P.Whh0[(size_t)r * HD + k];
  return P.Wih0[(size_t)r * (XDIM + EMBD) + XDIM + (k - HD)];
}
__device__ void run_A(const Params& P, int bid, uint32_t* smem){
  const int tid = threadIdx.x;
  const int w = tid >> 6, l = tid & 63;
  const int O = bid * 16 + w;
  float* xv = (float*)smem;                 // 1536 floats
  uint2* wl2 = (uint2*)(smem + 1664);       // words 1664..18047 (64 KB)
  float* h0loc = (float*)(smem + 18048);    // 16 floats
  uint32_t wr[4][8];
  uint32_t wry[4];
#pragma unroll
  for (int g = 0; g < 4; ++g){
    int r = g * HD + O;
#pragma unroll
    for (int p = 0; p < 8; ++p)
      wr[g][p] = packbf(asrc(P, r, 128 * p + 2 * l), asrc(P, r, 128 * p + 2 * l + 1));
#pragma unroll
    for (int q = 0; q < 2; ++q){
      uint2 u;
      u.x = packbf(asrc(P, r, 128 * (8 + 2 * q) + 2 * l), asrc(P, r, 128 * (8 + 2 * q) + 2 * l + 1));
      u.y = packbf(asrc(P, r, 128 * (9 + 2 * q) + 2 * l), asrc(P, r, 128 * (9 + 2 * q) + 2 * l + 1));
      wl2[(q * 4 + g) * 1024 + tid] = u;
    }
    wry[g] = packbf(P.Wfold[(size_t)r * 128 + 2 * l], P.Wfold[(size_t)r * 128 + 2 * l + 1]);
  }
  float cst = P.c0in[O];
  __syncthreads();
  for (int t = 0; t < T_STEPS; ++t){
    const float* pre = P.PRE + (size_t)t * 6144;     // plain loads (read-only, cached)
    float q0 = pre[O], q1 = pre[HD + O], q2 = pre[2 * HD + O], q3 = pre[3 * HD + O];
    // stage h0(t-1): tag >= t at parity (t-1)&1 (detect + fetch in one poll)
    if (tid < 768){
      u32x4 r = poll_rec(P.h0rec + ((t & 1) ^ 1) * 768 + tid, (uint32_t)t);
      xv[2 * tid] = __uint_as_float(r[0]);
      xv[2 * tid + 1] = __uint_as_float(r[1]);
    }
    __syncthreads();                         // barrier 1: xv staged
    float a0 = 0.f, a1 = 0.f, a2 = 0.f, a3 = 0.f;
#pragma unroll
    for (int p = 0; p < 8; ++p){
      float2 x2 = *(const float2*)&xv[128 * p + 2 * l];
      uint32_t u0 = wr[0][p], u1 = wr[1][p], u2 = wr[2][p], u3 = wr[3][p];
      a0 += bf_lo(u0) * x2.x + bf_hi(u0) * x2.y;
      a1 += bf_lo(u1) * x2.x + bf_hi(u1) * x2.y;
      a2 += bf_lo(u2) * x2.x + bf_hi(u2) * x2.y;
      a3 += bf_lo(u3) * x2.x + bf_hi(u3) * x2.y;
    }
#pragma unroll
    for (int q = 0; q < 2; ++q){
      float2 xa = *(const float2*)&xv[128 * (8 + 2 * q) + 2 * l];
      float2 xb = *(const float2*)&xv[128 * (9 + 2 * q) + 2 * l];
      uint2 u0 = wl2[(q * 4 + 0) * 1024 + tid];
      uint2 u1 = wl2[(q * 4 + 1) * 1024 + tid];
      uint2 u2 = wl2[(q * 4 + 2) * 1024 + tid];
      uint2 u3 = wl2[(q * 4 + 3) * 1024 + tid];
      a0 += bf_lo(u0.x) * xa.x + bf_hi(u0.x) * xa.y + bf_lo(u0.y) * xb.x + bf_hi(u0.y) * xb.y;
      a1 += bf_lo(u1.x) * xa.x + bf_hi(u1.x) * xa.y + bf_lo(u1.y) * xb.x + bf_hi(u1.y) * xb.y;
      a2 += bf_lo(u2.x) * xa.x + bf_hi(u2.x) * xa.y + bf_lo(u2.y) * xb.x + bf_hi(u2.y) * xb.y;
      a3 += bf_lo(u3.x) * xa.x + bf_hi(u3.x) * xa.y + bf_lo(u3.y) * xb.x + bf_hi(u3.y) * xb.y;
    }
    if (t > 0){                              // y(t-1): per-lane tagged poll, no barrier
      u32x4 r = poll_rec(P.yrec + ((t & 1) ^ 1) * 64 + l, (uint32_t)t);
      float y0 = __uint_as_float(r[0]), y1 = __uint_as_float(r[1]);
      a0 += bf_lo(wry[0]) * y0 + bf_hi(wry[0]) * y1;
      a1 += bf_lo(wry[1]) * y0 + bf_hi(wry[1]) * y1;
      a2 += bf_lo(wry[2]) * y0 + bf_hi(wry[2]) * y1;
      a3 += bf_lo(wry[3]) * y0 + bf_hi(wry[3]) * y1;
    }
#pragma unroll
    for (int m = 1; m < 64; m <<= 1){
      a0 += __shfl_xor(a0, m, 64);
      a1 += __shfl_xor(a1, m, 64);
      a2 += __shfl_xor(a2, m, 64);
      a3 += __shfl_xor(a3, m, 64);
    }
    float gi = sigm(a0 + q0);
    float gf = sigm(a1 + q1);
    float gg = tanhf(a2 + q2);
    float go = sigm(a3 + q3);
    cst = gf * cst + gi * gg;
    float hn = go * tanhf(cst);
    if (l == 0) h0loc[w] = hn;
    __syncthreads();                         // barrier 2: h0loc ready + xv protect
    if (tid < 8)                             // fire-and-forget tagged publish
      st_rec(P.h0rec + (t & 1) * 768 + bid * 8 + tid,
             h0loc[2 * tid], h0loc[2 * tid + 1], (uint32_t)(t + 1));
  }
}

// ---------------- group B: LSTM layer 1 + logit partials (128 blocks, 12 outputs) ----------------
// Staging h1(t-1) then (overlapped dot6) staging h0(t) — both tagged polls.
// Barrier-4 REMOVED vs round 6: partrec pairs assembled in-register via
// shfl_xor(pp,4); h1 pairs assembled in wave0 via 6 shfls. All publishes stay
// BUNCHED (~100 cyc after barrier 3) with unchanged record formats/counts.
__device__ __forceinline__ float bsrc(const Params& P, int r, int k){
  if (k < HD) return P.Wih1[(size_t)r * HD + k];
  return P.Whh1[(size_t)r * HD + (k - HD)];
}
__device__ void run_B(const Params& P, int bidb, uint32_t* smem){
  const int tid = threadIdx.x;
  const int w = tid >> 6, l = tid & 63;
  const int base = bidb * 12;
  float* xv = (float*)smem;                  // 3072 floats
  uint2* wl2 = (uint2*)(smem + 3072);        // words 3072..39935 (147456 B)
  float* g1 = (float*)(smem + 39936);        // 48
  float* c1 = (float*)(smem + 39984);        // 2*12 double-buffered
  uint32_t wr[3][12];
  float bias[3];
#pragma unroll
  for (int jj = 0; jj < 3; ++jj){
    int idx = 3 * w + jj;
    int g = idx / 12, o = idx % 12;
    int r = g * HD + base + o;
    bias[jj] = P.bih1[r] + P.bhh1[r];
#pragma unroll
    for (int p = 0; p < 12; ++p)
      wr[jj][p] = packbf(bsrc(P, r, 128 * p + 2 * l), bsrc(P, r, 128 * p + 2 * l + 1));
#pragma unroll
    for (int q = 0; q < 6; ++q){
      uint2 u;
      u.x = packbf(bsrc(P, r, 128 * (12 + 2 * q) + 2 * l), bsrc(P, r, 128 * (12 + 2 * q) + 2 * l + 1));
      u.y = packbf(bsrc(P, r, 128 * (13 + 2 * q) + 2 * l), bsrc(P, r, 128 * (13 + 2 * q) + 2 * l + 1));
      wl2[(q * 3 + jj) * 1024 + tid] = u;
    }
  }
  const int jrow = tid >> 2, cpart = tid & 3;
  float wc0 = 0.f, wc1 = 0.f, wc2 = 0.f;
  if (tid < 512){
    const float* wcp = P.Wc + (size_t)jrow * HD + base + cpart * 3;
    wc0 = wcp[0]; wc1 = wcp[1]; wc2 = wcp[2];
  }
  if (tid < 12) c1[12 + tid] = P.c0in[HD + base + tid];   // t=0 reads buffer 1
  __syncthreads();
  for (int t = 0; t < T_STEPS; ++t){
    // stage h1(t-1): tag >= t
    if (tid < 768){
      u32x4 r = poll_rec(P.h1rec + ((t & 1) ^ 1) * 768 + tid, (uint32_t)t);
      xv[1536 + 2 * tid] = __uint_as_float(r[0]);
      xv[1537 + 2 * tid] = __uint_as_float(r[1]);
    }
    __syncthreads();                         // barrier 1
    float a0 = 0.f, a1 = 0.f, a2 = 0.f;
#pragma unroll
    for (int q = 0; q < 6; ++q){             // h1 side (LDS weights) — overlapped phase
      float2 xa = *(const float2*)&xv[128 * (12 + 2 * q) + 2 * l];
      float2 xb = *(const float2*)&xv[128 * (13 + 2 * q) + 2 * l];
      uint2 u0 = wl2[(q * 3 + 0) * 1024 + tid];
      uint2 u1 = wl2[(q * 3 + 1) * 1024 + tid];
      uint2 u2 = wl2[(q * 3 + 2) * 1024 + tid];
      a0 += bf_lo(u0.x) * xa.x + bf_hi(u0.x) * xa.y + bf_lo(u0.y) * xb.x + bf_hi(u0.y) * xb.y;
      a1 += bf_lo(u1.x) * xa.x + bf_hi(u1.x) * xa.y + bf_lo(u1.y) * xb.x + bf_hi(u1.y) * xb.y;
      a2 += bf_lo(u2.x) * xa.x + bf_hi(u2.x) * xa.y + bf_lo(u2.y) * xb.x + bf_hi(u2.y) * xb.y;
    }
    // stage h0(t): tag >= t+1 (the A->B hop; detect+fetch fused)
    if (tid < 768){
      u32x4 r = poll_rec(P.h0rec + (t & 1) * 768 + tid, (uint32_t)(t + 1));
      xv[2 * tid] = __uint_as_float(r[0]);
      xv[2 * tid + 1] = __uint_as_float(r[1]);
    }
    __syncthreads();                         // barrier 2
#pragma unroll
    for (int p = 0; p < 12; ++p){            // h0 side (reg weights) — serial phase
      float2 x2 = *(const float2*)&xv[128 * p + 2 * l];
      uint32_t u0 = wr[0][p], u1 = wr[1][p], u2 = wr[2][p];
      a0 += bf_lo(u0) * x2.x + bf_hi(u0) * x2.y;
      a1 += bf_lo(u1) * x2.x + bf_hi(u1) * x2.y;
      a2 += bf_lo(u2) * x2.x + bf_hi(u2) * x2.y;
    }
#pragma unroll
    for (int m = 1; m < 64; m <<= 1){
      a0 += __shfl_xor(a0, m, 64);
      a1 += __shfl_xor(a1, m, 64);
      a2 += __shfl_xor(a2, m, 64);
    }
    if (l == 0){
      g1[3 * w + 0] = a0 + bias[0];
      g1[3 * w + 1] = a1 + bias[1];
      g1[3 * w + 2] = a2 + bias[2];
    }
    __syncthreads();                         // barrier 3
    const int par = ((t & 1) ^ 1) * 12, cur = (t & 1) * 12;
    uint32_t tg = (uint32_t)(t + 1);
    if (tid < 512){                          // fused gate + bunched-publish phase
      float h[3], cc[3];
#pragma unroll
      for (int ii = 0; ii < 3; ++ii){
        int o = cpart * 3 + ii;
        float gi = sigm(g1[o]);
        float gf = sigm(g1[12 + o]);
        float gg = tanhf(g1[24 + o]);
        float go = sigm(g1[36 + o]);
        float c = gf * c1[par + o] + gi * gg;
        cc[ii] = c;
        h[ii] = go * tanhf(c);
      }
      float pp = wc0 * h[0] + wc1 * h[1] + wc2 * h[2];
      pp += __shfl_xor(pp, 1, 64);
      pp += __shfl_xor(pp, 2, 64);           // all 4 cpart lanes hold pp(jrow)
      float pp2 = __shfl_xor(pp, 4, 64);     // pair with jrow^1 (same wave)
      if ((tid & 7) == 0)                    // thread 8r: publish {logit 2r, 2r+1}
        st_rec(P.partrec + (size_t)(t & 1) * 8192 + bidb * 64 + (tid >> 3), pp, pp2, tg);
      if (jrow == 0){                        // tid 0..3: c-state writeback
#pragma unroll
        for (int ii = 0; ii < 3; ++ii) c1[cur + cpart * 3 + ii] = cc[ii];
      }
      if (w == 0){                           // wave0: assemble + publish 6 h1 records
        // lane r (r<6) publishes {out 2r, out 2r+1}; out j held by lane j/3 (<4)
        int j0 = 2 * l, j1 = 2 * l + 1;
        int s0 = j0 / 3, i0 = j0 % 3, s1 = j1 / 3, i1 = j1 % 3;
        float A0 = __shfl(h[0], s0, 64), B0 = __shfl(h[1], s0, 64), C0 = __shfl(h[2], s0, 64);
        float A1 = __shfl(h[0], s1, 64), B1 = __shfl(h[1], s1, 64), C1 = __shfl(h[2], s1, 64);
        float o0 = (i0 == 0) ? A0 : ((i0 == 1) ? B0 : C0);
        float o1 = (i1 == 0) ? A1 : ((i1 == 1) ? B1 : C1);
        if (l < 6)
          st_rec(P.h1rec + (t & 1) * 768 + bidb * 6 + l, o0, o1, tg);
      }
    }
    // overwrite safety (no barrier 4): next-step writers of xv/g1/c1 are all
    // ordered behind barriers 1-3 of step t+1, which every wave reaches only
    // after completing its step-t reads. Publishes carry in-band tags.
  }
}

// ---------------- group C: logit reduce + softmax + y + out (1 block, 1 barrier/step) ----------------
__device__ void run_C(const Params& P, uint32_t* smem){
  const int tid = threadIdx.x;
  float* partred = (float*)smem;             // 2048
  float* bcs = (float*)(smem + 2048);        // 128
  const int w = tid >> 6, l = tid & 63;
  const int g8 = tid >> 6, j2 = tid & 63;    // 16 groups x 64
  if (tid < 128) bcs[tid] = P.bc[tid];
  __syncthreads();
  for (int t = 0; t < T_STEPS; ++t){
    const uint4* base = P.partrec + (size_t)(t & 1) * 8192;
    uint32_t tg = (uint32_t)(t + 1);
    u32x4 rec[8];
    uint32_t done = 0, n = 0;
    while (done != 0xFFu){                   // parallel poll: issue all stale, wait once
#pragma unroll
      for (int k = 0; k < 8; ++k)
        if (!(done & (1u << k))) rec[k] = rec_issue(base + (size_t)(8 * g8 + k) * 64 + j2);
      asm volatile("s_waitcnt vmcnt(0)" ::: "memory");
      __builtin_amdgcn_sched_barrier(0);     // pin the tag checks after the waitcnt
#pragma unroll
      for (int k = 0; k < 8; ++k)
        if (rec[k][2] >= tg) done |= (1u << k);
      if (done != 0xFFu){
        __builtin_amdgcn_s_sleep(2);
        if (++n > 2000000u) break;           // hang guard
      }
    }
    float s0 = 0.f, s1 = 0.f;
#pragma unroll
    for (int k = 0; k < 8; ++k){
      s0 += __uint_as_float(rec[k][0]);
      s1 += __uint_as_float(rec[k][1]);
    }
    partred[g8 * 128 + 2 * j2] = s0;
    partred[g8 * 128 + 2 * j2 + 1] = s1;
    __syncthreads();                         // the only barrier
    if (w == 0){                             // wave0 finishes the step alone
      float lt0 = bcs[2 * l], lt1 = bcs[2 * l + 1];
#pragma unroll
      for (int g = 0; g < 16; ++g){
        lt0 += partred[g * 128 + 2 * l];
        lt1 += partred[g * 128 + 2 * l + 1];
      }
      float m = fmaxf(lt0, lt1);
#pragma unroll
      for (int k = 1; k < 64; k <<= 1) m = fmaxf(m, __shfl_xor(m, k, 64));
      float e0 = __expf(lt0 - m), e1 = __expf(lt1 - m);
      float sd = e0 + e1;
#pragma unroll
      for (int k = 1; k < 64; k <<= 1) sd += __shfl_xor(sd, k, 64);
      float inv = 1.f / sd;
      float y0 = e0 * inv, y1 = e1 * inv;
      P.out[(size_t)t * 128 + 2 * l] = y0;   // host-only consumer: plain stores
      P.out[(size_t)t * 128 + 2 * l + 1] = y1;
      st_rec(P.yrec + (t & 1) * 64 + l, y0, y1, tg);
    }
    // next-step partred overwrite is gated transitively: tag t+2 requires B(t+1)
    // which requires A(t+1)'s y-poll of y(t), published after wave0's reads above.
  }
}

__global__ __launch_bounds__(1024) void k_lstm(Params P){
  extern __shared__ __align__(16) uint32_t smem[];
  int bid = blockIdx.x;
  if (bid < NA) run_A(P, bid, smem);
  else if (bid < NA + NB) run_B(P, bid - NA, smem);
  else run_C(P, smem);
}

// ---------------- pre-kernels ----------------
__global__ void k_init(const float* h0in, uint4* h0rec, uint4* h1rec,
                       uint4* partrec, uint4* yrec){
  int tid = threadIdx.x;
  for (int i = tid; i < 768; i += 256){
    uint4 r0; r0.x = __float_as_uint(h0in[2 * i]); r0.y = __float_as_uint(h0in[2 * i + 1]);
    r0.z = 0u; r0.w = 0u;
    h0rec[i] = r0; h0rec[768 + i] = r0;
    uint4 r1; r1.x = __float_as_uint(h0in[HD + 2 * i]); r1.y = __float_as_uint(h0in[HD + 2 * i + 1]);
    r1.z = 0u; r1.w = 0u;
    h1rec[i] = r1; h1rec[768 + i] = r1;
  }
  uint4 z; z.x = 0u; z.y = 0u; z.z = 0u; z.w = 0u;
  for (int i = tid; i < 16384; i += 256) partrec[i] = z;
  for (int i = tid; i < 128; i += 256) yrec[i] = z;
}

// Wfold[r][j] = sum_e Wih0[r][118+e] * Wmap[e][j]; bfold[r] = sum_e Wih0[r][118+e]*bmap[e]
__global__ void k_fold(const float* Wih0, const float* Wmap, const float* bmap,
                       float* Wfold, float* bfold){
  __shared__ float we[64 * 128];
  int b = blockIdx.x, tid = threadIdx.x;
  int r0 = b * 64;
  for (int i = tid; i < 64 * 128; i += 256){
    int rr = i >> 7, e = i & 127;
    we[i] = Wih0[(size_t)(r0 + rr) * (XDIM + EMBD) + XDIM + e];
  }
  __syncthreads();
  int j = tid & 127, half = tid >> 7;
  float acc[32];
#pragma unroll
  for (int rr = 0; rr < 32; ++rr) acc[rr] = 0.f;
  for (int e = 0; e < 128; ++e){
    float wv = Wmap[(size_t)e * 128 + j];
#pragma unroll
    for (int rr = 0; rr < 32; ++rr) acc[rr] += we[(half * 32 + rr) * 128 + e] * wv;
  }
  for (int rr = 0; rr < 32; ++rr)
    Wfold[(size_t)(r0 + half * 32 + rr) * 128 + j] = acc[rr];
  if (tid < 64){
    float a = 0.f;
    for (int e = 0; e < 128; ++e) a += we[tid * 128 + e] * bmap[e];
    bfold[r0 + tid] = a;
  }
}

// PRE[t][r] = b_ih0[r]+b_hh0[r] + (t>0 ? bfold[r] : 0) + sum_{k<118} W_ih0[r][k]*x[t][k]
__global__ void k_pre(const float* x, const float* Wih0, const float* bih0, const float* bhh0,
                      const float* bfold, float* PRE){
  int tb = blockIdx.x >> 2;
  int rc = blockIdx.x & 3;
  int tid = threadIdx.x;
  __shared__ float xl[32 * XDIM];
  for (int i = tid; i < 32 * XDIM; i += 256){
    int tt = i / XDIM, k = i % XDIM;
    xl[i] = x[(size_t)(tb * 32 + tt) * XDIM + k];
  }
  __syncthreads();
  for (int rr = 0; rr < 6; ++rr){
    int r = rc * HD + rr * 256 + tid;
    float acc[32];
#pragma unroll
    for (int t = 0; t < 32; ++t) acc[t] = 0.f;
    const float* wrow = Wih0 + (size_t)r * (XDIM + EMBD);
    for (int k = 0; k < XDIM; ++k){
      float wv = wrow[k];
#pragma unroll
      for (int t = 0; t < 32; ++t) acc[t] += wv * xl[t * XDIM + k];
    }
    float bb = bih0[r] + bhh0[r];
    float bf = bfold[r];
    for (int t = 0; t < 32; ++t)
      PRE[(size_t)(tb * 32 + t) * 6144 + r] = acc[t] + bb + ((tb * 32 + t) > 0 ? bf : 0.f);
  }
}

// Wc = W_out @ W_hl (128x1536, K=1024); bc = W_out @ b_hl + b_out
__global__ void k_wc(const float* Whl, const float* Wout, const float* bhl, const float* bout,
                     float* Wc, float* bc){
  if (blockIdx.x == 96){
    int j = threadIdx.x;
    if (j < 128){
      float a = 0.f;
      for (int m = 0; m < 1024; ++m) a += Wout[(size_t)j * 1024 + m] * bhl[m];
      bc[j] = a + bout[j];
    }
    return;
  }
  int kt = blockIdx.x % 6, jt = blockIdx.x / 6;
  __shared__ float wo[8 * 1024];
  int tid = threadIdx.x;
  for (int i = tid; i < 8 * 1024; i += 256) wo[i] = Wout[(size_t)(jt * 8) * 1024 + i];
  __syncthreads();
  int k = kt * 256 + tid;
  float acc[8];
#pragma unroll
  for (int jj = 0; jj < 8; ++jj) acc[jj] = 0.f;
  for (int m = 0; m < 1024; ++m){
    float wl = Whl[(size_t)m * HD + k];
#pragma unroll
    for (int jj = 0; jj < 8; ++jj) acc[jj] += wo[jj * 1024 + m] * wl;
  }
#pragma unroll
  for (int jj = 0; jj < 8; ++jj) Wc[(size_t)(jt * 8 + jj) * HD + k] = acc[jj];
}

__global__ void k_sentinel(float* out){ out[0] = 1.0e6f; }

extern "C" void kernel_launch(void* const* d_in, const int* in_sizes, int n_in,
                              void* d_out, int out_size, void* d_ws, size_t ws_size,
                              hipStream_t stream){
  (void)in_sizes; (void)n_in; (void)out_size;
  const float* x    = (const float*)d_in[0];
  const float* h0in = (const float*)d_in[1];
  const float* c0in = (const float*)d_in[2];
  const float* Wih0 = (const float*)d_in[3];
  const float* Whh0 = (const float*)d_in[4];
  const float* bih0 = (const float*)d_in[5];
  const float* bhh0 = (const float*)d_in[6];
  const float* Wih1 = (const float*)d_in[7];
  const float* Whh1 = (const float*)d_in[8];
  const float* bih1 = (const float*)d_in[9];
  const float* bhh1 = (const float*)d_in[10];
  const float* Whl  = (const float*)d_in[11];
  const float* bhl  = (const float*)d_in[12];
  const float* Wout = (const float*)d_in[13];
  const float* bout = (const float*)d_in[14];
  const float* Wmap = (const float*)d_in[15];
  const float* bmap = (const float*)d_in[16];
  float* out = (float*)d_out;
  float* ws = (float*)d_ws;

  size_t off = 0;
  float* PRE    = ws + off; off += (size_t)T_STEPS * 6144;
  float* Wc     = ws + off; off += 128 * HD;
  float* bc     = ws + off; off += 128;
  float* Wfold  = ws + off; off += (size_t)6144 * 128;
  float* bfold  = ws + off; off += 6144;
  off = (off + 3) & ~(size_t)3;              // 16B alignment for records
  uint4* h0rec   = (uint4*)(ws + off); off += 2 * 768 * 4;
  uint4* h1rec   = (uint4*)(ws + off); off += 2 * 768 * 4;
  uint4* partrec = (uint4*)(ws + off); off += 2 * 8192 * 4;
  uint4* yrec    = (uint4*)(ws + off); off += 2 * 64 * 4;

  if (ws_size < off * sizeof(float) + 1024){
    hipLaunchKernelGGL(k_sentinel, dim3(1), dim3(1), 0, stream, out);
    return;
  }

  // opt-in to >64KB dynamic LDS (160 KiB/CU on gfx950); unconditional, idempotent
  (void)hipFuncSetAttribute(reinterpret_cast<const void*>(k_lstm),
                            hipFuncAttributeMaxDynamicSharedMemorySize, SMEM_BYTES);

  hipLaunchKernelGGL(k_init, dim3(1), dim3(256), 0, stream, h0in, h0rec, h1rec, partrec, yrec);
  hipLaunchKernelGGL(k_fold, dim3(96), dim3(256), 0, stream, Wih0, Wmap, bmap, Wfold, bfold);
  hipLaunchKernelGGL(k_pre, dim3(256), dim3(256), 0, stream, x, Wih0, bih0, bhh0, bfold, PRE);
  hipLaunchKernelGGL(k_wc, dim3(97), dim3(256), 0, stream, Whl, Wout, bhl, bout, Wc, bc);

  Params P;
  P.x = x; P.h0in = h0in; P.c0in = c0in;
  P.Wih0 = Wih0; P.Whh0 = Whh0; P.bih0 = bih0; P.bhh0 = bhh0;
  P.Wih1 = Wih1; P.Whh1 = Whh1; P.bih1 = bih1; P.bhh1 = bhh1;
  P.Whl = Whl; P.bhl = bhl; P.Wout = Wout; P.bout = bout;
  P.Wfold = Wfold;
  P.PRE = PRE; P.Wc = Wc; P.bc = bc;
  P.h0rec = h0rec; P.h1rec = h1rec; P.partrec = partrec; P.yrec = yrec;
  P.out = out;

  hipLaunchKernelGGL(k_lstm, dim3(NBLK), dim3(1024), SMEM_BYTES, stream, P);
}